// Round 11
// baseline (313.772 us; speedup 1.0000x reference)
//
#include <hip/hip_runtime.h>

typedef __attribute__((ext_vector_type(8))) short short8;
typedef __attribute__((ext_vector_type(4))) float f32x4;
typedef __attribute__((ext_vector_type(4))) unsigned int u32x4;
union frag_u { short8 v; unsigned short u[8]; unsigned int w[4]; };

__device__ __forceinline__ float bf2f(unsigned short b) {
  unsigned int u = ((unsigned int)b) << 16;
  float f; __builtin_memcpy(&f, &u, 4); return f;
}
__device__ __forceinline__ unsigned short f2bf(float f) {
  unsigned int u; __builtin_memcpy(&u, &f, 4);
  return (unsigned short)((u + 0x7FFFu + ((u >> 16) & 1u)) >> 16);
}
__device__ __forceinline__ unsigned short hi_of(float f) { return f2bf(f); }
__device__ __forceinline__ unsigned short lo_of(float f) {
  unsigned short h = f2bf(f); return f2bf(f - bf2f(h));
}
__device__ __forceinline__ float ldf_f32(const void* p, int i) { return ((const float*)p)[i]; }
__device__ __forceinline__ float ldf_b16(const void* p, int i) { return bf2f(((const unsigned short*)p)[i]); }

// Trans-reduced LSTM activation (proven in an earlier round: same absmax).
__device__ __forceinline__ void lstm_act(float gi, float gf, float gg, float go,
                                         float& c, float& h) {
  gi = fminf(fmaxf(gi, -15.f), 15.f);
  gf = fminf(fmaxf(gf, -15.f), 15.f);
  gg = fminf(fmaxf(gg, -15.f), 15.f);
  go = fminf(fmaxf(go, -15.f), 15.f);
  float A = 1.f + __expf(-gf);
  float B = 1.f + __expf(-gi);
  float C = 1.f + __expf(2.f * gg);
  float BC = B * C;
  float num = c * BC + A * (C - 2.f);
  c = num * __builtin_amdgcn_rcpf(A * BC);
  float D = 1.f + __expf(-go);
  float cl = fminf(fmaxf(c, -15.f), 15.f);
  float E = 1.f + __expf(2.f * cl);
  h = (E - 2.f) * __builtin_amdgcn_rcpf(D * E);
}

// Fallback dtype detector. flag: 0 = bf16, 1 = f32.
__global__ void detect_dtype_kernel(const unsigned short* s, int* flag) {
  int i = threadIdx.x;   // 64 threads
  unsigned short v = s[2 * i];
  int e = (v >> 7) & 0xFF;
  unsigned long long m = __ballot(e < 100 || e > 140);
  if (i == 0) *flag = (__popcll(m) >= 16) ? 1 : 0;
}

// ===================== LSTM weight element (A-operand layout) ==============
// MFMA roles: A = weights (m = permuted gate-output), B = state (n = row).
// Output map: m = 16T + 4*qd + r  <->  u = 4T + O[qd], g = r  (O = {1,2,3,0})
//   -> lane (n, quad) receives the full (i,f,g,o) of its OWN item u=4T+O[quad].
// K layout (K = 192, unified for both dtypes; bf16 uses lo = 0):
//  k 0..20  : x tri-product, d=k/3, slot k%3: (Wx_hi,x_hi),(Wx_hi,x_lo),(Wx_lo,x_hi)
//  k 21,22  : bias (hi,lo) paired with constant 1.0 ; k23 = 0
//  k 24..127: region A: 13 windows wA (8 k = 4 u-pairs (W_hi,h_hi),(W_hi,h_lo)),
//             window wA read by B-quad (3+wA)&3, u = 4*(4*(wA>>2)+s) + O[qB]
//             (capacity: quad3 t<=12, others t<=11; u=49 overflows to region B)
//  k 128..191: region B: 8 windows wB, B-quad = wB&3, singles (W_lo,h_hi),
//             t = 8*(wB>>2)+j ; special wB==4 j=5,6 = overflow pair for u=49.
// Every window's h-values are OWNED by the reading lane -> B-frags are built
// from the lane's own pk[] registers; no cross-lane gate/h movement at all.
template <bool F32>
__device__ __forceinline__ unsigned short W_elem(
    int k, int T, int nl,
    const void* wih_, const void* whh_, const void* bih_, const void* bhh_) {
  const int O[4] = {1, 2, 3, 0};
  int qd = nl >> 2, g = nl & 3;
  int uc = 4 * T + O[qd];
  if (uc >= 50) return 0;                  // invalid output column
  int no = g * 50 + uc;                    // original weight column
  auto whi = [&](const void* p, int idx) -> unsigned short {
    if constexpr (F32) return hi_of(((const float*)p)[idx]);
    else return ((const unsigned short*)p)[idx];
  };
  auto wlo = [&](const void* p, int idx) -> unsigned short {
    if constexpr (F32) return lo_of(((const float*)p)[idx]);
    else return 0;
  };
  if (k < 21) {
    int d = k / 3, sl = k - 3 * d;
    return (sl == 2) ? wlo(wih_, d * 200 + no) : whi(wih_, d * 200 + no);
  }
  if (k < 23) {
    float b;
    if constexpr (F32) b = ((const float*)bih_)[no] + ((const float*)bhh_)[no];
    else b = bf2f(((const unsigned short*)bih_)[no]) + bf2f(((const unsigned short*)bhh_)[no]);
    if (k == 21) return f2bf(b);
    unsigned short bh = f2bf(b);
    return f2bf(b - bf2f(bh));
  }
  if (k < 24) return 0;
  if (k < 128) {
    int idx = k - 24, wA = idx >> 3, s = (idx & 7) >> 1;
    int qB = (3 + wA) & 3, t = 4 * (wA >> 2) + s;
    if (t > ((qB == 3) ? 12 : 11)) return 0;
    int u = 4 * t + O[qB];
    if (u >= 50) return 0;
    return whi(whh_, u * 200 + no);
  }
  int idx = k - 128, wB = idx >> 3, j7 = idx & 7;
  int qB = wB & 3, t = 8 * (wB >> 2) + j7;
  if (wB == 4 && j7 >= 5)                  // overflow pair for u=49
    return (j7 <= 6) ? whi(whh_, 49 * 200 + no) : 0;
  if (t > ((qB == 0 || qB == 3) ? 12 : 11)) return 0;
  int u = 4 * t + O[qB];
  if (u >= 50) return 0;
  return wlo(whh_, u * 200 + no);
}

// ===================== tail MLP helpers (4-wave cooperative) ===============
// sA(16 x Kpad bf16, stride AS) @ W(K x N) -> sG[n][m]  (G stride 20)
template <int AS, typename GetB, typename GetW>
__device__ __forceinline__ void mfma_layer(const unsigned short* sA, float* sG,
    int wave, int col, int quad, int kc_n, int ntiles, int N, GetB getb, GetW getw)
{
  for (int tile = wave; tile < ntiles; tile += 4) {
    int nn = tile * 16 + col;
    float b = (nn < N) ? getb(nn) : 0.f;
    f32x4 acc = {b, b, b, b};
    for (int kc = 0; kc < kc_n; ++kc) {
      short8 a = *(const short8*)&sA[col * AS + kc * 32 + quad * 8];
      frag_u w;
      #pragma unroll
      for (int j = 0; j < 8; ++j) {
        int k = kc * 32 + quad * 8 + j;
        w.u[j] = (nn < N) ? getw(k, nn) : (unsigned short)0;
      }
      acc = __builtin_amdgcn_mfma_f32_16x16x32_bf16(a, w.v, acc, 0, 0, 0);
    }
    *(f32x4*)&sG[nn * 20 + quad * 4] = acc;
  }
}

template <int AS>
__device__ __forceinline__ void relu_fill(const float* sG, unsigned short* sA,
                                          int tid, int N, int loOff, int Kpad) {
  for (int idx = tid; idx < 16 * Kpad; idx += 256) {
    int m = idx & 15, nn = idx >> 4;
    unsigned short v = 0;
    if (nn < N) {
      v = f2bf(fmaxf(sG[nn * 20 + m], 0.f));
    } else if (nn >= loOff && nn < loOff + N) {
      float x = fmaxf(sG[(nn - loOff) * 20 + m], 0.f);
      v = lo_of(x);
    }
    sA[m * AS + nn] = v;
  }
}

// ===================== fused kernel: register-resident LSTM + tail =========
// 256 threads / 4 waves, 16 rows per block, grid = 512.
// Waves split the 13 gate-tiles {4,3,3,3}; per step each wave: build B-frags
// from own registers (~50 VALU), 18-24 MFMA (weights persistent in regs),
// in-register activation of 3-4 items/lane, 13-word LDS pk-exchange, ONE
// 4-wave barrier. No gate/h LDS round-trip, no block-wide convoy.
template <bool F32>
__global__ __launch_bounds__(256, 2) void value_net_kernel(
    const void* state_, const void* wih_, const void* whh_,
    const void* bih_, const void* bhh_,
    const void* w1_, const void* b1_, const void* w2_, const void* b2_,
    const void* w3_, const void* b3_, const void* w4_, const void* b4_,
    void* out_, const int* flag)
{
  if (flag && *flag != (F32 ? 1 : 0)) return;

  constexpr int AS = 328;

  __shared__ __align__(16) unsigned int sX[1024 * 8];      // packed (x_hi|x_lo) 32KB
  __shared__ unsigned int sE[2][13 * 64];                  // pk exchange (dbuf)
  __shared__ __align__(16) unsigned short sA[16 * AS];     // tail joint/acts
  __shared__ __align__(16) float sG[208 * 20];             // tail G

  const unsigned short* st16 = (const unsigned short*)state_;
  const float*          stf  = (const float*)state_;

  const int tid  = threadIdx.x;
  const int wv   = tid >> 6;           // 0..3
  const int lane = tid & 63;
  const int n    = lane & 15;          // batch row within tile
  const int quad = lane >> 4;
  const int r0   = blockIdx.x * 16;

  const int O[4] = {1, 2, 3, 0};
  const int ores = O[quad];
  const int tb   = (wv == 0) ? 0 : (wv == 1) ? 4 : (wv == 2) ? 7 : 10;
  const int nt   = (wv == 0) ? 4 : 3;

  auto ldf = [&](const void* p, int i) -> float {
    if constexpr (F32) return ldf_f32(p, i); else return ldf_b16(p, i);
  };

  // ---- stage packed x slab ----
  for (int idx = tid; idx < 1024; idx += 256) {
    int t = idx >> 4, r = idx & 15;
    size_t g = (size_t)(r0 + r) * 832 + (size_t)t * 13 + 6;
    unsigned int* dst = &sX[(t * 16 + r) * 8];
    #pragma unroll
    for (int d = 0; d < 7; ++d) {
      unsigned int v;
      if constexpr (F32) {
        float f = stf[g + d];
        unsigned short h = f2bf(f);
        v = (unsigned int)h | ((unsigned int)f2bf(f - bf2f(h)) << 16);
      } else v = st16[g + d];
      dst[d] = v;
    }
    dst[7] = 0;
  }

  // ---- persistent weight A-fragments: wf[Ti][kc], tiles T = tb+Ti ----
  frag_u wf[4][6];
  #pragma unroll
  for (int Ti = 0; Ti < 4; ++Ti) {
    if (Ti < nt) {
      int T = tb + Ti;
      #pragma unroll
      for (int kc = 0; kc < 6; ++kc)
        #pragma unroll
        for (int j = 0; j < 8; ++j)
          wf[Ti][kc].u[j] = W_elem<F32>(kc * 32 + quad * 8 + j, T, n,
                                        wih_, whh_, bih_, bhh_);
    }
  }

  unsigned int pk[16];
  #pragma unroll
  for (int i = 0; i < 16; ++i) pk[i] = 0;   // h0 = 0
  float c_[4] = {0.f, 0.f, 0.f, 0.f};

  __syncthreads();   // sX ready

  auto hh = [](unsigned int a, unsigned int b) -> unsigned int {
    return (a & 0xffffu) | (b << 16);
  };
  auto ror16 = [](unsigned int a) -> unsigned int {
    return (a >> 16) | (a << 16);
  };
  auto packh = [](float h) -> unsigned int {
    unsigned short hb = f2bf(h);
    unsigned short hl = f2bf(h - bf2f(hb));
    return (unsigned int)hb | ((unsigned int)hl << 16);
  };

  // ---- LSTM: 64 steps ----
  #pragma unroll 1
  for (int tt = 0; tt < 64; ++tt) {
    const u32x4* xp = (const u32x4*)&sX[(tt * 16 + n) * 8];
    u32x4 xa = xp[0], xb = xp[1];
    unsigned int px0 = xa[0], px1 = xa[1], px2 = xa[2], px3 = xa[3];
    unsigned int px4 = xb[0], px5 = xb[1], px6 = xb[2];
    const unsigned int ONE = 0x3F80u;

    frag_u fr0, fr1, fr2, fr3, fr4, fr5;
    if (quad == 0) {
      fr0.w[0] = px0; fr0.w[1] = hh(px0, px1); fr0.w[2] = ror16(px1); fr0.w[3] = px2;
    } else if (quad == 1) {
      fr0.w[0] = hh(px2, px3); fr0.w[1] = ror16(px3); fr0.w[2] = px4; fr0.w[3] = hh(px4, px5);
    } else if (quad == 2) {
      fr0.w[0] = ror16(px5); fr0.w[1] = px6; fr0.w[2] = hh(px6, ONE); fr0.w[3] = ONE;
    } else {
      fr0.w[0] = pk[0]; fr0.w[1] = pk[1]; fr0.w[2] = pk[2]; fr0.w[3] = pk[3];
    }
    bool q3 = (quad == 3);
    fr1.w[0] = q3 ? pk[4]  : pk[0];  fr1.w[1] = q3 ? pk[5]  : pk[1];
    fr1.w[2] = q3 ? pk[6]  : pk[2];  fr1.w[3] = q3 ? pk[7]  : pk[3];
    fr2.w[0] = q3 ? pk[8]  : pk[4];  fr2.w[1] = q3 ? pk[9]  : pk[5];
    fr2.w[2] = q3 ? pk[10] : pk[6];  fr2.w[3] = q3 ? pk[11] : pk[7];
    fr3.w[0] = q3 ? pk[12] : pk[8];  fr3.w[1] = q3 ? 0u     : pk[9];
    fr3.w[2] = q3 ? 0u     : pk[10]; fr3.w[3] = q3 ? 0u     : pk[11];
    fr4.w[0] = hh(pk[0], pk[1]); fr4.w[1] = hh(pk[2], pk[3]);
    fr4.w[2] = hh(pk[4], pk[5]); fr4.w[3] = hh(pk[6], pk[7]);
    fr5.w[0] = hh(pk[8], pk[9]); fr5.w[1] = hh(pk[10], pk[11]);
    if (quad == 0) { fr5.w[2] = hh(pk[12], pk[12]); fr5.w[3] = pk[12] >> 16; }
    else           { fr5.w[2] = hh(pk[12], 0u);     fr5.w[3] = 0u; }

    f32x4 z = {0.f, 0.f, 0.f, 0.f};
    f32x4 acc0 = z, acc1 = z, acc2 = z, acc3 = z;
    #pragma unroll
    for (int kc = 0; kc < 6; ++kc) {
      const frag_u& fr = (kc == 0) ? fr0 : (kc == 1) ? fr1 : (kc == 2) ? fr2 :
                         (kc == 3) ? fr3 : (kc == 4) ? fr4 : fr5;
      acc0 = __builtin_amdgcn_mfma_f32_16x16x32_bf16(wf[0][kc].v, fr.v, acc0, 0, 0, 0);
      acc1 = __builtin_amdgcn_mfma_f32_16x16x32_bf16(wf[1][kc].v, fr.v, acc1, 0, 0, 0);
      acc2 = __builtin_amdgcn_mfma_f32_16x16x32_bf16(wf[2][kc].v, fr.v, acc2, 0, 0, 0);
      if (wv == 0)
        acc3 = __builtin_amdgcn_mfma_f32_16x16x32_bf16(wf[3][kc].v, fr.v, acc3, 0, 0, 0);
    }

    // in-register activation of this lane's items
    unsigned int pknew0 = 0, pknew1 = 0, pknew2 = 0, pknew3 = 0;
    { int u = 4 * (tb + 0) + ores;
      if (u < 50) { float h; lstm_act(acc0[0], acc0[1], acc0[2], acc0[3], c_[0], h); pknew0 = packh(h); } }
    { int u = 4 * (tb + 1) + ores;
      if (u < 50) { float h; lstm_act(acc1[0], acc1[1], acc1[2], acc1[3], c_[1], h); pknew1 = packh(h); } }
    { int u = 4 * (tb + 2) + ores;
      if (u < 50) { float h; lstm_act(acc2[0], acc2[1], acc2[2], acc2[3], c_[2], h); pknew2 = packh(h); } }
    if (wv == 0) { float h; lstm_act(acc3[0], acc3[1], acc3[2], acc3[3], c_[3], h); pknew3 = packh(h); }

    if (tt < 63) {
      unsigned int* e = sE[tt & 1];
      if      (wv == 0) { e[0 + lane] = pknew0; e[64 + lane] = pknew1; e[128 + lane] = pknew2; e[192 + lane] = pknew3; }
      else if (wv == 1) { e[256 + lane] = pknew0; e[320 + lane] = pknew1; e[384 + lane] = pknew2; }
      else if (wv == 2) { e[448 + lane] = pknew0; e[512 + lane] = pknew1; e[576 + lane] = pknew2; }
      else              { e[640 + lane] = pknew0; e[704 + lane] = pknew1; e[768 + lane] = pknew2; }
    }
    if      (wv == 0) { pk[0] = pknew0; pk[1] = pknew1; pk[2] = pknew2; pk[3] = pknew3; }
    else if (wv == 1) { pk[4] = pknew0; pk[5] = pknew1; pk[6] = pknew2; }
    else if (wv == 2) { pk[7] = pknew0; pk[8] = pknew1; pk[9] = pknew2; }
    else              { pk[10] = pknew0; pk[11] = pknew1; pk[12] = pknew2; }
    if (tt < 63) {
      __syncthreads();
      const unsigned int* e = sE[tt & 1];
      if (wv == 0) {
        pk[4] = e[256 + lane]; pk[5] = e[320 + lane]; pk[6] = e[384 + lane];
        pk[7] = e[448 + lane]; pk[8] = e[512 + lane]; pk[9] = e[576 + lane];
        pk[10] = e[640 + lane]; pk[11] = e[704 + lane]; pk[12] = e[768 + lane];
      } else if (wv == 1) {
        pk[0] = e[0 + lane]; pk[1] = e[64 + lane]; pk[2] = e[128 + lane]; pk[3] = e[192 + lane];
        pk[7] = e[448 + lane]; pk[8] = e[512 + lane]; pk[9] = e[576 + lane];
        pk[10] = e[640 + lane]; pk[11] = e[704 + lane]; pk[12] = e[768 + lane];
      } else if (wv == 2) {
        pk[0] = e[0 + lane]; pk[1] = e[64 + lane]; pk[2] = e[128 + lane]; pk[3] = e[192 + lane];
        pk[4] = e[256 + lane]; pk[5] = e[320 + lane]; pk[6] = e[384 + lane];
        pk[10] = e[640 + lane]; pk[11] = e[704 + lane]; pk[12] = e[768 + lane];
      } else {
        pk[0] = e[0 + lane]; pk[1] = e[64 + lane]; pk[2] = e[128 + lane]; pk[3] = e[192 + lane];
        pk[4] = e[256 + lane]; pk[5] = e[320 + lane]; pk[6] = e[384 + lane];
        pk[7] = e[448 + lane]; pk[8] = e[512 + lane]; pk[9] = e[576 + lane];
      }
    }
  }

  // ---- tail MLP (4-wave cooperative, unified F32-style joint layout) ----
  // joint: [self_hi(0..5) | h_hi(6..55) | self_lo(56..61) | h_lo(62..111)]
  {
    unsigned int* a32 = (unsigned int*)sA;
    for (int idx = tid; idx < 16 * AS / 2; idx += 256) a32[idx] = 0;
  }
  __syncthreads();
  {
    auto jput = [&](int t, unsigned int p) {
      int u = 4 * t + ores;
      if (u < 50) {
        sA[n * AS + 6 + u]  = (unsigned short)(p & 0xffffu);
        sA[n * AS + 62 + u] = (unsigned short)(p >> 16);
      }
    };
    if      (wv == 0) { jput(0, pk[0]); jput(1, pk[1]); jput(2, pk[2]); jput(3, pk[3]); }
    else if (wv == 1) { jput(4, pk[4]); jput(5, pk[5]); jput(6, pk[6]); }
    else if (wv == 2) { jput(7, pk[7]); jput(8, pk[8]); jput(9, pk[9]); }
    else              { jput(10, pk[10]); jput(11, pk[11]); jput(12, pk[12]); }
  }
  if (tid < 96) {
    int m = tid / 6, d = tid - (tid / 6) * 6;
    if constexpr (F32) {
      float f = stf[(size_t)(r0 + m) * 832 + d];
      sA[m * AS + d] = hi_of(f); sA[m * AS + 56 + d] = lo_of(f);
    } else {
      sA[m * AS + d] = st16[(size_t)(r0 + m) * 832 + d];
    }
  }
  __syncthreads();

  auto whiT = [&](const void* p, int idx) -> unsigned short {
    if constexpr (F32) return hi_of(((const float*)p)[idx]);
    else return ((const unsigned short*)p)[idx];
  };

  // L1: -> 150 (K = 112 -> 128)
  mfma_layer<AS>(sA, sG, wv, n, quad, 4, 10, 150,
    [&](int nn) { return ldf(b1_, nn); },
    [&](int k, int nn) -> unsigned short {
      if (k < 56)  return whiT(w1_, k * 150 + nn);
      if (k < 112) return whiT(w1_, (k - 56) * 150 + nn);
      return (unsigned short)0;
    });
  __syncthreads();
  relu_fill<AS>(sG, sA, tid, 150, 150, 320);
  __syncthreads();

  // L2: 150 -> 100 (hi|lo K = 300 -> 320)
  mfma_layer<AS>(sA, sG, wv, n, quad, 10, 7, 100,
    [&](int nn) { return ldf(b2_, nn); },
    [&](int k, int nn) -> unsigned short {
      if (k < 150) return whiT(w2_, k * 100 + nn);
      if (k < 300) return whiT(w2_, (k - 150) * 100 + nn);
      return (unsigned short)0;
    });
  __syncthreads();
  relu_fill<AS>(sG, sA, tid, 100, 100, 224);
  __syncthreads();

  // L3: 100 -> 100 (K = 200 -> 224)
  mfma_layer<AS>(sA, sG, wv, n, quad, 7, 7, 100,
    [&](int nn) { return ldf(b3_, nn); },
    [&](int k, int nn) -> unsigned short {
      if (k < 100) return whiT(w3_, k * 100 + nn);
      if (k < 200) return whiT(w3_, (k - 100) * 100 + nn);
      return (unsigned short)0;
    });
  __syncthreads();

  // L4: relu(sG) @ w4 + b4 on wave 0
  if (tid < 64) {
    int m = lane & 15, j0 = lane >> 4;
    float s = 0.f;
    for (int j = j0; j < 100; j += 4)
      s += fmaxf(sG[j * 20 + m], 0.f) * ldf(w4_, j);
    s += __shfl_xor(s, 16);
    s += __shfl_xor(s, 32);
    if (lane < 16) {
      float v = s + ldf(b4_, 0);
      if constexpr (!F32) ((unsigned short*)out_)[r0 + m] = f2bf(v);
      else                ((float*)out_)[r0 + m] = v;
    }
  }
}

extern "C" void kernel_launch(void* const* d_in, const int* in_sizes, int n_in,
                              void* d_out, int out_size, void* d_ws, size_t ws_size,
                              hipStream_t stream) {
  (void)n_in; (void)out_size;
  // d_in[1..10] (mlp1_* / attn_*) are dead code in the reference — unused.
  const void* state = d_in[0];
  const void* wih = d_in[11]; const void* whh = d_in[12];
  const void* bih = d_in[13]; const void* bhh = d_in[14];
  const void* w1  = d_in[15]; const void* b1  = d_in[16];
  const void* w2  = d_in[17]; const void* b2  = d_in[18];
  const void* w3  = d_in[19]; const void* b3  = d_in[20];
  const void* w4  = d_in[21]; const void* b4  = d_in[22];

  const long long F32B  = 8192LL * 64 * 13 * 4;
  const long long BF16B = 8192LL * 64 * 13 * 2;
  long long sz = in_sizes ? (long long)in_sizes[0] : -1;

  if (sz == F32B) {
    value_net_kernel<true><<<dim3(512), dim3(256), 0, stream>>>(
        state, wih, whh, bih, bhh, w1, b1, w2, b2, w3, b3, w4, b4, d_out,
        (const int*)nullptr);
  } else if (sz == BF16B) {
    value_net_kernel<false><<<dim3(512), dim3(256), 0, stream>>>(
        state, wih, whh, bih, bhh, w1, b1, w2, b2, w3, b3, w4, b4, d_out,
        (const int*)nullptr);
  } else if (ws_size >= sizeof(int)) {
    int* flag = (int*)d_ws;
    detect_dtype_kernel<<<dim3(1), dim3(64), 0, stream>>>(
        (const unsigned short*)state, flag);
    value_net_kernel<false><<<dim3(512), dim3(256), 0, stream>>>(
        state, wih, whh, bih, bhh, w1, b1, w2, b2, w3, b3, w4, b4, d_out, flag);
    value_net_kernel<true><<<dim3(512), dim3(256), 0, stream>>>(
        state, wih, whh, bih, bhh, w1, b1, w2, b2, w3, b3, w4, b4, d_out, flag);
  } else {
    value_net_kernel<false><<<dim3(512), dim3(256), 0, stream>>>(
        state, wih, whh, bih, bhh, w1, b1, w2, b2, w3, b3, w4, b4, d_out,
        (const int*)nullptr);
  }
}